// Round 8
// baseline (43.443 us; speedup 1.0000x reference)
//
#include <hip/hip_runtime.h>

// Depth-4 path signature, N=64, L=512, C=8. Output/batch:
// [sig1(8) | sig2(64) | sig3(512) | sig4(4096)] = 4680 f32.
//
// Single fused kernel, grid 256 = (batch n) x (l-quarter lq), 1024 thr = 16 waves.
// R8 = R7 with the SPILL FIX, structure otherwise identical:
//   R6/R7 showed VGPR_Count 36-40 vs ~50 live floats => scratch spills
//   (WRITE_SIZE 4.2MB vs 1.2MB output). Cause: 58KB LDS allows 2 blocks/CU,
//   backend targets 8 waves/SIMD -> 64-VGPR budget -> spill. Fix: dynamic
//   LDS padded to 84KB (forces 1 block/CU = 4 waves/SIMD, which our grid
//   1 block/CU already implies) + amdgpu_waves_per_eu(4,4) -> 128-VGPR
//   budget -> state fits in registers.
//   Stage:   dx[511*8] -> LDS via 1022 parallel float4 diffs.
//   Phase A: wave w scans chunk w (32 segs), 2 uniform ds_read_b128/step;
//            lvl1-3 scan + lvl4 acc for this block's l-pair, all in regs.
//   Phase B: each wave folds prefix chunks 0..w-1 (lvl1-3 Chen) from LDS.
//   Phase C: D4 = B4 + A3*B1[l] + A2*B2[kl] + A1*B3[jkl] -> LDS atomicAdd.
//   wave15/lq0: final fold -> lvl1-3 out. Tail: copy lvl4 accumulator out.

static constexpr int L = 512;
static constexpr int NC = 8;
static constexpr int NSEG = L - 1;               // 511
static constexpr int SIG = 8 + 64 + 512 + 4096;  // 4680
static constexpr int DXF = NSEG * NC;            // 4088 floats
static constexpr int SLOT = 592;                 // 8 lvl1 + 64 lvl2 + 520 lvl3(stride65)
static constexpr int SLOTOFF = DXF;              // 4088
static constexpr int L4OFF = SLOTOFF + 16 * SLOT;  // 13560
static constexpr size_t LDS_BYTES = 86016;       // 84 KB: force 1 block/CU

__device__ __forceinline__ float sel8(float d0, float d1, float d2, float d3,
                                      float d4, float d5, float d6, float d7,
                                      bool b0, bool b1, bool b2) {
    float x0 = b0 ? d1 : d0;
    float x1 = b0 ? d3 : d2;
    float x2 = b0 ? d5 : d4;
    float x3 = b0 ? d7 : d6;
    float y0 = b1 ? x1 : x0;
    float y1 = b1 ? x3 : x2;
    return b2 ? y1 : y0;
}

__global__ __launch_bounds__(1024)
__attribute__((amdgpu_waves_per_eu(4, 4)))
void sig_fused3(const float* __restrict__ path, float* __restrict__ out) {
    extern __shared__ __align__(16) float lds[];
    const int tid = threadIdx.x;
    const int w = tid >> 6;        // wave = chunk 0..15
    const int lane = tid & 63;
    const int i = lane >> 3;
    const int j = lane & 7;
    const int n = blockIdx.x >> 2;   // batch
    const int lq = blockIdx.x & 3;   // l-quarter: l = lq*2, lq*2+1

    // ---- stage dx into LDS (independent parallel loads) + zero l4 acc ----
    {
        const float4* pv = reinterpret_cast<const float4*>(path + (size_t)n * (L * NC));
        if (tid < DXF / 4) {  // 1022 float4 diffs
            const float4 a = pv[tid];
            const float4 b = pv[tid + 2];
            *reinterpret_cast<float4*>(&lds[tid * 4]) =
                make_float4(b.x - a.x, b.y - a.y, b.z - a.z, b.w - a.w);
        }
        lds[L4OFF + tid] = 0.f;
    }
    __syncthreads();

    // ---------------- Phase A: chunk scan (LDS-fed) ----------------
    const int seg0 = w * 32;
    const int len = min(32, NSEG - seg0);

    const bool ib0 = lane & 8, ib1 = lane & 16, ib2 = lane & 32;
    const bool jb0 = lane & 1, jb1 = lane & 2, jb2 = lane & 4;
    const bool lb0 = lq & 1, lb1 = lq & 2;

    float s1 = 0.f, s2 = 0.f;
    float s3[8];
    float2 acc[8];
#pragma unroll
    for (int k = 0; k < 8; ++k) {
        s3[k] = 0.f;
        acc[k] = make_float2(0.f, 0.f);
    }
    constexpr float c3 = 1.f / 6.f;
    constexpr float c4 = 1.f / 24.f;

    const float* dbase = lds + seg0 * 8;
#pragma unroll 4
    for (int s = 0; s < len; ++s) {
        const float4 A = *reinterpret_cast<const float4*>(dbase + s * 8);
        const float4 B = *reinterpret_cast<const float4*>(dbase + s * 8 + 4);
        const float d0 = A.x, d1 = A.y, d2 = A.z, d3 = A.w;
        const float d4 = B.x, d5 = B.y, d6 = B.z, d7 = B.w;

        const float di = sel8(d0, d1, d2, d3, d4, d5, d6, d7, ib0, ib1, ib2);
        const float dj = sel8(d0, d1, d2, d3, d4, d5, d6, d7, jb0, jb1, jb2);
        const float ea = lb0 ? d2 : d0, eb = lb0 ? d6 : d4;
        const float dl0 = lb1 ? eb : ea;
        const float ec = lb0 ? d3 : d1, ed = lb0 ? d7 : d5;
        const float dl1 = lb1 ? ed : ec;

        const float u = fmaf(s1, c3, di * c4);    // s1/6 + di/24
        float vv = fmaf(s1, dj * 0.5f, s2);       // s2 + s1*dj/2
        vv = fmaf(di * dj, c3, vv);               // + di*dj/6
        const float w_ = fmaf(s2, 0.5f, dj * u);  // s2/2 + dj*u

#define KSTEP(kk, dval)                                   \
    {                                                     \
        const float Cc = fmaf((dval), w_, s3[kk]);        \
        acc[kk].x = fmaf(dl0, Cc, acc[kk].x);             \
        acc[kk].y = fmaf(dl1, Cc, acc[kk].y);             \
        s3[kk] = fmaf((dval), vv, s3[kk]);                \
    }
        KSTEP(0, d0) KSTEP(1, d1) KSTEP(2, d2) KSTEP(3, d3)
        KSTEP(4, d4) KSTEP(5, d5) KSTEP(6, d6) KSTEP(7, d7)
#undef KSTEP
        s2 = fmaf(dj, fmaf(di, 0.5f, s1), s2);
        s1 += di;
    }

    // write chunk lvl1-3 to LDS slot w; lvl3 layout [t1*65 + t2*8 + t3]
    {
        float* sp = lds + SLOTOFF + w * SLOT;
        if (j == 0) sp[i] = s1;
        sp[8 + i * 8 + j] = s2;
        float* s3p = sp + 72 + i * 65 + j * 8;
#pragma unroll
        for (int k = 0; k < 8; ++k) s3p[k] = s3[k];
    }
    __syncthreads();

    // ---------------- Phase B: prefix fold (lvl1-3, Chen) ----------------
    float a1 = 0.f, a2 = 0.f;
    float a3[8];
#pragma unroll
    for (int k = 0; k < 8; ++k) a3[k] = 0.f;

#define FOLD123(BP)                                                          \
    {                                                                        \
        const float4 b1lo = *reinterpret_cast<const float4*>(BP);            \
        const float4 b1hi = *reinterpret_cast<const float4*>((BP) + 4);      \
        const float4 r0 = *reinterpret_cast<const float4*>((BP) + 8 + j * 8);\
        const float4 r1 = *reinterpret_cast<const float4*>((BP) + 12 + j * 8);\
        const float b1i = (BP)[i], b1j = (BP)[j];                            \
        const float b2ij = (BP)[8 + i * 8 + j];                              \
        const float* b3p = (BP) + 72 + i * 65 + j * 8;                       \
        a3[0] = fmaf(a2, b1lo.x, fmaf(a1, r0.x, a3[0] + b3p[0]));            \
        a3[1] = fmaf(a2, b1lo.y, fmaf(a1, r0.y, a3[1] + b3p[1]));            \
        a3[2] = fmaf(a2, b1lo.z, fmaf(a1, r0.z, a3[2] + b3p[2]));            \
        a3[3] = fmaf(a2, b1lo.w, fmaf(a1, r0.w, a3[3] + b3p[3]));            \
        a3[4] = fmaf(a2, b1hi.x, fmaf(a1, r1.x, a3[4] + b3p[4]));            \
        a3[5] = fmaf(a2, b1hi.y, fmaf(a1, r1.y, a3[5] + b3p[5]));            \
        a3[6] = fmaf(a2, b1hi.z, fmaf(a1, r1.z, a3[6] + b3p[6]));            \
        a3[7] = fmaf(a2, b1hi.w, fmaf(a1, r1.w, a3[7] + b3p[7]));            \
        a2 = fmaf(a1, b1j, a2 + b2ij);                                       \
        a1 += b1i;                                                           \
    }

    {
        const float* bp = lds + SLOTOFF;
        for (int b = 0; b < w; ++b, bp += SLOT) FOLD123(bp)
    }

    // ---------------- Phase C: lvl4 contribution + LDS atomic sum --------
    {
        const float* cp = lds + SLOTOFF + w * SLOT;
        const float B1l0 = cp[lq * 2], B1l1 = cp[lq * 2 + 1];
        float* l4 = lds + L4OFF + lane * 2;
#pragma unroll
        for (int k = 0; k < 8; ++k) {
            const float B2a = cp[8 + k * 8 + lq * 2];
            const float B2b = cp[8 + k * 8 + lq * 2 + 1];
            const float B3a = cp[72 + j * 65 + k * 8 + lq * 2];
            const float B3b = cp[72 + j * 65 + k * 8 + lq * 2 + 1];
            float vx = fmaf(a3[k], B1l0, fmaf(a2, B2a, fmaf(a1, B3a, acc[k].x)));
            float vy = fmaf(a3[k], B1l1, fmaf(a2, B2b, fmaf(a1, B3b, acc[k].y)));
            atomicAdd(&l4[k * 128 + 0], vx);
            atomicAdd(&l4[k * 128 + 1], vy);
        }
    }

    // ---------------- final lvl1-3 (wave 15, lq 0) ----------------------
    if (w == 15 && lq == 0) {
        const float* bp = lds + SLOTOFF + 15 * SLOT;
        FOLD123(bp)
        float* o = out + (size_t)n * SIG;
        float4 st0, st1;
        st0.x = a3[0]; st0.y = a3[1]; st0.z = a3[2]; st0.w = a3[3];
        st1.x = a3[4]; st1.y = a3[5]; st1.z = a3[6]; st1.w = a3[7];
        *reinterpret_cast<float4*>(o + 72 + i * 64 + j * 8) = st0;
        *reinterpret_cast<float4*>(o + 72 + i * 64 + j * 8 + 4) = st1;
        o[8 + i * 8 + j] = a2;
        if (j == 0) o[i] = a1;
    }
#undef FOLD123

    __syncthreads();

    // ---------------- write lvl4 (this block's l-pair) ------------------
    if (tid < 512) {
        const int kk = tid >> 6;
        const int ln = tid & 63;
        const int tri = (ln >> 3) * 64 + (ln & 7) * 8 + kk;
        const float2 v = *reinterpret_cast<const float2*>(&lds[L4OFF + kk * 128 + ln * 2]);
        *reinterpret_cast<float2*>(out + (size_t)n * SIG + 584 + tri * 8 + lq * 2) = v;
    }
}

extern "C" void kernel_launch(void* const* d_in, const int* in_sizes, int n_in,
                              void* d_out, int out_size, void* d_ws, size_t ws_size,
                              hipStream_t stream) {
    const float* path = (const float*)d_in[0];
    float* out = (float*)d_out;
    // Allow >64KB dynamic LDS (idempotent, deterministic; not a banned call).
    (void)hipFuncSetAttribute((const void*)sig_fused3,
                              hipFuncAttributeMaxDynamicSharedMemorySize,
                              (int)LDS_BYTES);
    // 64 batches x 4 l-quarters = 256 blocks (1 per CU), 1024 threads each
    sig_fused3<<<256, 1024, LDS_BYTES, stream>>>(path, out);
}

// Round 9
// 20.429 us; speedup vs baseline: 2.1265x; 2.1265x over previous
//
#include <hip/hip_runtime.h>

// Depth-4 path signature, N=64, L=512, C=8. Output/batch:
// [sig1(8) | sig2(64) | sig3(512) | sig4(4096)] = 4680 f32.
//
// Single fused kernel, grid 256 = (batch n) x (k-quarter kq), 1024 thr = 16 waves.
// R9 changes vs R8 (structure else identical):
//  * k-pair split (not l-pair): lvl4 elements (i,j,k in pair, ALL l) per block
//    -> per (i,j): 16 consecutive output floats = full 64B lines, coalesced
//    float4 stores (R8's WRITE_SIZE=4242KB was 4x RMW amplification of
//    scattered float2 stores; FETCH included RMW line fetches).
//  * No LDS atomics: phase C stores per-wave contributions to
//    contrib[w][c*64+lane] (conflict-free), then a deterministic 16-way
//    strided reduction + stride-17 LDS transpose -> coalesced output.
//  * Fold state per thread shrinks to {a1, a2, a3 x2} (9 FMA/fold).
// Phases: stage dx->LDS | A: wave w scans chunk w (32 segs, lvl1-3 full +
// lvl4 acc for k-pair, regs) | slot lvl1-3 -> LDS | B: exclusive prefix fold
// | C: D4 = B4 + A3*B1[l] + A2*B2[k,l] + A1*B3[j,k,l] -> contrib | reduce ->
// transpose -> coalesced lvl4 writes; wave15 writes lvl1-3 (k-slice of lvl3).

static constexpr int L = 512;
static constexpr int NC = 8;
static constexpr int NSEG = L - 1;                 // 511
static constexpr int SIG = 8 + 64 + 512 + 4096;    // 4680
static constexpr int DXF = NSEG * NC;              // 4088 floats
static constexpr int SLOTOFF = DXF;                // 4088
static constexpr int SLOT = 592;                   // 8 + 64 + 520 (lvl3 stride 65)
static constexpr int CONTRIB = SLOTOFF + 16 * SLOT;  // 13560
static constexpr int TRANSO = CONTRIB + 16 * 1024;   // 29944
static constexpr int LDSF = TRANSO + 64 * 17 + 16;   // 31048 floats
static constexpr size_t LDS_BYTES = (size_t)LDSF * sizeof(float);  // ~121 KB

__device__ __forceinline__ float sel8(float d0, float d1, float d2, float d3,
                                      float d4, float d5, float d6, float d7,
                                      bool b0, bool b1, bool b2) {
    float x0 = b0 ? d1 : d0;
    float x1 = b0 ? d3 : d2;
    float x2 = b0 ? d5 : d4;
    float x3 = b0 ? d7 : d6;
    float y0 = b1 ? x1 : x0;
    float y1 = b1 ? x3 : x2;
    return b2 ? y1 : y0;
}

__global__ __launch_bounds__(1024)
void sig_ksplit(const float* __restrict__ path, float* __restrict__ out) {
    extern __shared__ __align__(16) float lds[];
    const int tid = threadIdx.x;
    const int w = tid >> 6;          // wave = chunk 0..15
    const int lane = tid & 63;       // (i,j)
    const int i = lane >> 3;
    const int j = lane & 7;
    const int n = blockIdx.x >> 2;   // batch
    const int kq = blockIdx.x & 3;   // k-quarter: k = kq*2, kq*2+1
    const int ka0 = kq * 2, ka1 = ka0 + 1;

    // ---- stage dx into LDS (independent parallel loads) ----
    {
        const float4* pv = reinterpret_cast<const float4*>(path + (size_t)n * (L * NC));
        if (tid < DXF / 4) {  // 1022 float4 diffs
            const float4 a = pv[tid];
            const float4 b = pv[tid + 2];
            *reinterpret_cast<float4*>(&lds[tid * 4]) =
                make_float4(b.x - a.x, b.y - a.y, b.z - a.z, b.w - a.w);
        }
    }
    __syncthreads();

    // ---------------- Phase A: chunk scan (LDS-fed) ----------------
    const int seg0 = w * 32;
    const int len = min(32, NSEG - seg0);

    const bool ib0 = lane & 8, ib1 = lane & 16, ib2 = lane & 32;
    const bool jb0 = lane & 1, jb1 = lane & 2, jb2 = lane & 4;
    const bool kb0 = kq & 1, kb1 = kq & 2;

    float s1 = 0.f, s2 = 0.f, s3a = 0.f, s3b = 0.f;
    float s3[8];
    float accA[8], accB[8];
#pragma unroll
    for (int k = 0; k < 8; ++k) {
        s3[k] = 0.f;
        accA[k] = 0.f;
        accB[k] = 0.f;
    }
    constexpr float c3 = 1.f / 6.f;
    constexpr float c4 = 1.f / 24.f;

    const float* dbase = lds + seg0 * 8;
#pragma unroll 4
    for (int s = 0; s < len; ++s) {
        const float4 A = *reinterpret_cast<const float4*>(dbase + s * 8);
        const float4 B = *reinterpret_cast<const float4*>(dbase + s * 8 + 4);
        float dd[8];
        dd[0] = A.x; dd[1] = A.y; dd[2] = A.z; dd[3] = A.w;
        dd[4] = B.x; dd[5] = B.y; dd[6] = B.z; dd[7] = B.w;

        const float di = sel8(dd[0], dd[1], dd[2], dd[3], dd[4], dd[5], dd[6], dd[7],
                              ib0, ib1, ib2);
        const float dj = sel8(dd[0], dd[1], dd[2], dd[3], dd[4], dd[5], dd[6], dd[7],
                              jb0, jb1, jb2);
        // dk0 = dd[2*kq], dk1 = dd[2*kq+1] (block-uniform selection)
        const float xa = kb0 ? dd[2] : dd[0], xb = kb0 ? dd[6] : dd[4];
        const float dk0 = kb1 ? xb : xa;
        const float ya = kb0 ? dd[3] : dd[1], yb = kb0 ? dd[7] : dd[5];
        const float dk1 = kb1 ? yb : ya;

        const float u = fmaf(s1, c3, di * c4);    // s1/6 + di/24
        float vv = fmaf(s1, dj * 0.5f, s2);       // s2 + s1*dj/2
        vv = fmaf(di * dj, c3, vv);               // + di*dj/6
        const float w_ = fmaf(s2, 0.5f, dj * u);  // s2/2 + dj*u

        const float Cc0 = fmaf(dk0, w_, s3a);     // uses OLD s3[ka0]
        const float Cc1 = fmaf(dk1, w_, s3b);

#pragma unroll
        for (int l = 0; l < 8; ++l) {
            accA[l] = fmaf(dd[l], Cc0, accA[l]);
            accB[l] = fmaf(dd[l], Cc1, accB[l]);
            s3[l] = fmaf(dd[l], vv, s3[l]);
        }
        s3a = fmaf(dk0, vv, s3a);
        s3b = fmaf(dk1, vv, s3b);
        s2 = fmaf(dj, fmaf(di, 0.5f, s1), s2);
        s1 += di;
    }

    // write chunk lvl1-3 to LDS slot w; lvl3 layout [t1*65 + t2*8 + t3]
    {
        float* sp = lds + SLOTOFF + w * SLOT;
        if (j == 0) sp[i] = s1;
        sp[8 + i * 8 + j] = s2;
        float* s3p = sp + 72 + i * 65 + j * 8;
#pragma unroll
        for (int k = 0; k < 8; ++k) s3p[k] = s3[k];
    }
    __syncthreads();

    // ---------------- Phase B: exclusive prefix fold (Chen, lvl1-3) ------
    float a1 = 0.f, a2 = 0.f, a3A = 0.f, a3B = 0.f;
    {
        const float* bp = lds + SLOTOFF;
        for (int b = 0; b < w; ++b, bp += SLOT) {
            const float b1i = bp[i], b1j = bp[j];
            const float b1k0 = bp[ka0], b1k1 = bp[ka1];
            const float b2ij = bp[8 + i * 8 + j];
            const float b2jk0 = bp[8 + j * 8 + ka0];
            const float b2jk1 = bp[8 + j * 8 + ka1];
            const float b3a = bp[72 + i * 65 + j * 8 + ka0];
            const float b3b = bp[72 + i * 65 + j * 8 + ka1];
            a3A = fmaf(a2, b1k0, fmaf(a1, b2jk0, a3A + b3a));
            a3B = fmaf(a2, b1k1, fmaf(a1, b2jk1, a3B + b3b));
            a2 = fmaf(a1, b1j, a2 + b2ij);
            a1 += b1i;
        }
    }

    // ---------------- Phase C: contribution -> contrib[w][c*64+lane] -----
    {
        const float* cp = lds + SLOTOFF + w * SLOT;
        float* cb = lds + CONTRIB + w * 1024 + lane;
#pragma unroll
        for (int l = 0; l < 8; ++l) {
            const float b1l = cp[l];
            const float b2a = cp[8 + ka0 * 8 + l];
            const float b2b = cp[8 + ka1 * 8 + l];
            const float b3a = cp[72 + j * 65 + ka0 * 8 + l];
            const float b3b = cp[72 + j * 65 + ka1 * 8 + l];
            const float va = fmaf(a3A, b1l, fmaf(a2, b2a, fmaf(a1, b3a, accA[l])));
            const float vb = fmaf(a3B, b1l, fmaf(a2, b2b, fmaf(a1, b3b, accB[l])));
            cb[l * 64] = va;          // c = 0*8 + l
            cb[(8 + l) * 64] = vb;    // c = 1*8 + l
        }
    }

    // ---------------- final lvl1-3 (wave 15; lvl3 k-slice per block) -----
    if (w == 15) {
        const float* bp = lds + SLOTOFF + 15 * SLOT;
        const float b1i = bp[i], b1j = bp[j];
        const float b1k0 = bp[ka0], b1k1 = bp[ka1];
        const float b2ij = bp[8 + i * 8 + j];
        const float b2jk0 = bp[8 + j * 8 + ka0];
        const float b2jk1 = bp[8 + j * 8 + ka1];
        const float b3a = bp[72 + i * 65 + j * 8 + ka0];
        const float b3b = bp[72 + i * 65 + j * 8 + ka1];
        a3A = fmaf(a2, b1k0, fmaf(a1, b2jk0, a3A + b3a));
        a3B = fmaf(a2, b1k1, fmaf(a1, b2jk1, a3B + b3b));
        a2 = fmaf(a1, b1j, a2 + b2ij);
        a1 += b1i;
        float* o = out + (size_t)n * SIG;
        o[72 + i * 64 + j * 8 + ka0] = a3A;
        o[72 + i * 64 + j * 8 + ka1] = a3B;
        if (kq == 0) {
            o[8 + i * 8 + j] = a2;
            if (j == 0) o[i] = a1;
        }
    }
    __syncthreads();

    // ---------------- reduce over w, transpose, coalesced store ----------
    {
        float s = 0.f;
        const float* c0 = lds + CONTRIB + tid;
#pragma unroll
        for (int ww = 0; ww < 16; ++ww) s += c0[ww * 1024];
        lds[TRANSO + (tid & 63) * 17 + (tid >> 6)] = s;
    }
    __syncthreads();
    if (tid < 256) {
        const int lp = tid >> 2, cq = tid & 3;
        const float* tp = lds + TRANSO + lp * 17 + cq * 4;
        float4 r;
        r.x = tp[0]; r.y = tp[1]; r.z = tp[2]; r.w = tp[3];
        *reinterpret_cast<float4*>(out + (size_t)n * SIG + 584 + lp * 64 + kq * 16 + cq * 4) = r;
    }
}

extern "C" void kernel_launch(void* const* d_in, const int* in_sizes, int n_in,
                              void* d_out, int out_size, void* d_ws, size_t ws_size,
                              hipStream_t stream) {
    const float* path = (const float*)d_in[0];
    float* out = (float*)d_out;
    (void)hipFuncSetAttribute((const void*)sig_ksplit,
                              hipFuncAttributeMaxDynamicSharedMemorySize,
                              (int)LDS_BYTES);
    // 64 batches x 4 k-quarters = 256 blocks (1 per CU), 1024 threads each
    sig_ksplit<<<256, 1024, LDS_BYTES, stream>>>(path, out);
}